// Round 8
// baseline (351.503 us; speedup 1.0000x reference)
//
#include <hip/hip_runtime.h>
#include <hip/hip_bf16.h>

// B=4, T=2048, E=768, H=12, hd=64.
// Round 8:
//   - GEMMs: round-7 global_load_lds versions (kept; ~40us win measured)
//   - attn: occupancy-targeted restructure. 64 q rows/block (16/wave),
//     single-buffered K/V (18.4KB LDS -> 8 blocks/CU cap), 1536 blocks
//     (6/CU avg vs 3 before), __launch_bounds__(256,8) -> 64 VGPR (the
//     faster round-6 operating point). Swapped-QK^T softmax, reg prefetch
//     across the two barriers.

#define BB 4
#define TT 2048
#define EE 768
#define HH 12
#define HD 64
#define KK 768
#define BTE (BB*TT*EE)  // 6291456

typedef __attribute__((ext_vector_type(8))) short bf16x8;
typedef __attribute__((ext_vector_type(4))) float f32x4;
typedef __attribute__((ext_vector_type(4))) int i32x4;

#define QSC 0.18033688011112042f   // 0.125 * log2(e)

#define GLOAD16(gp, lp) \
    __builtin_amdgcn_global_load_lds( \
        (const __attribute__((address_space(1))) unsigned*)(gp), \
        (__attribute__((address_space(3))) unsigned*)(lp), 16, 0, 0)

static __device__ __forceinline__ unsigned short f2bf(float f) {
    unsigned u = __builtin_bit_cast(unsigned, f);
    u += 0x7fffu + ((u >> 16) & 1u);   // RNE
    return (unsigned short)(u >> 16);
}

static __device__ __forceinline__ unsigned cvt_pk_bf16(float lo, float hi) {
    unsigned r;
    asm("v_cvt_pk_bf16_f32 %0, %1, %2" : "=v"(r) : "v"(lo), "v"(hi));
    return r;
}

// ---------------------------------------------------------------------------
__global__ __launch_bounds__(256)
void convx_kernel(const float* __restrict__ x, unsigned short* __restrict__ xb) {
    const size_t i = ((size_t)blockIdx.x * 256 + threadIdx.x) * 8;
    float4 a = *(const float4*)&x[i];
    float4 b = *(const float4*)&x[i + 4];
    ushort4 lo, hi;
    lo.x = f2bf(a.x); lo.y = f2bf(a.y); lo.z = f2bf(a.z); lo.w = f2bf(a.w);
    hi.x = f2bf(b.x); hi.y = f2bf(b.y); hi.z = f2bf(b.z); hi.w = f2bf(b.w);
    *(ushort4*)&xb[i] = lo;
    *(ushort4*)&xb[i + 4] = hi;
}

// ---------------------------------------------------------------------------
__global__ __launch_bounds__(256)
void transw_kernel(const float* __restrict__ W, unsigned short* __restrict__ Wt, int N) {
    __shared__ unsigned short Ts[64][72];
    const int n0 = blockIdx.x * 64;
    const int k0 = blockIdx.y * 64;
    const int tid = threadIdx.x;
    {
        const int r = tid >> 4;
        const int c4 = (tid & 15) << 2;
#pragma unroll
        for (int i = 0; i < 4; ++i) {
            const int k = r + i * 16;
            float4 w4 = *(const float4*)&W[(size_t)(k0 + k) * N + n0 + c4];
            Ts[k][c4 + 0] = f2bf(w4.x); Ts[k][c4 + 1] = f2bf(w4.y);
            Ts[k][c4 + 2] = f2bf(w4.z); Ts[k][c4 + 3] = f2bf(w4.w);
        }
    }
    __syncthreads();
#pragma unroll
    for (int i = 0; i < 2; ++i) {
        const int idx = tid + i * 256;
        const int n = idx >> 3;
        const int ch = idx & 7;
        ushort4 p0, p1;
        p0.x = Ts[ch * 8 + 0][n]; p0.y = Ts[ch * 8 + 1][n];
        p0.z = Ts[ch * 8 + 2][n]; p0.w = Ts[ch * 8 + 3][n];
        p1.x = Ts[ch * 8 + 4][n]; p1.y = Ts[ch * 8 + 5][n];
        p1.z = Ts[ch * 8 + 6][n]; p1.w = Ts[ch * 8 + 7][n];
        *(ushort4*)&Wt[(size_t)(n0 + n) * KK + k0 + ch * 8] = p0;
        *(ushort4*)&Wt[(size_t)(n0 + n) * KK + k0 + ch * 8 + 4] = p1;
    }
}

// ---------------------------------------------------------------------------
// bf16 MFMA GEMM, m97-style (round 7, unchanged).
// ---------------------------------------------------------------------------
template<int MODE>
__global__ __launch_bounds__(256)
void mfma_gemm_kernel(const unsigned short* __restrict__ A,
                      const unsigned short* __restrict__ Wt,
                      unsigned short* __restrict__ q_ws,
                      unsigned short* __restrict__ k_ws,
                      unsigned short* __restrict__ v_ws,
                      float* __restrict__ outf) {
    __shared__ __align__(16) unsigned short As[128 * 32];   // linear, 64B rows
    __shared__ __align__(16) unsigned short Bs[128 * 32];
    const int bx = blockIdx.x;
    const int by = blockIdx.y;
    const int tid = threadIdx.x;
    const int w = tid >> 6, lane = tid & 63;
    const int c = lane & 15, g = lane >> 4;
    const int wr = w >> 1, wc = w & 1;
    const int m0 = by * 128, n0 = bx * 128;

    const int lrow = lane >> 2;        // 0..15
    const int lch  = (lane & 3) * 8;   // shorts within 32-elem row

    const unsigned short* Ap = A  + (size_t)m0 * KK;
    const unsigned short* Bp = Wt + (size_t)n0 * KK;

    f32x4 acc[4][4] = {};

    for (int kt = 0; kt < KK / 32; ++kt) {
        const int k0 = kt * 32;
        __syncthreads();
        GLOAD16(Ap + (size_t)(w * 32 +  0 + lrow) * KK + k0 + lch, &As[(w * 32 +  0) * 32]);
        GLOAD16(Ap + (size_t)(w * 32 + 16 + lrow) * KK + k0 + lch, &As[(w * 32 + 16) * 32]);
        GLOAD16(Bp + (size_t)(w * 32 +  0 + lrow) * KK + k0 + lch, &Bs[(w * 32 +  0) * 32]);
        GLOAD16(Bp + (size_t)(w * 32 + 16 + lrow) * KK + k0 + lch, &Bs[(w * 32 + 16) * 32]);
        __syncthreads();

        bf16x8 af[4], bfr[4];
#pragma unroll
        for (int m = 0; m < 4; ++m)
            af[m] = *(const bf16x8*)&As[(wr * 64 + m * 16 + c) * 32 + g * 8];
#pragma unroll
        for (int n = 0; n < 4; ++n)
            bfr[n] = *(const bf16x8*)&Bs[(wc * 64 + n * 16 + c) * 32 + g * 8];
#pragma unroll
        for (int m = 0; m < 4; ++m)
#pragma unroll
            for (int n = 0; n < 4; ++n)
                acc[m][n] = __builtin_amdgcn_mfma_f32_16x16x32_bf16(af[m], bfr[n], acc[m][n], 0, 0, 0);
    }

    if (MODE == 0) {
        const int which = n0 / EE;
        const int h = (n0 % EE) / HD + wc;
        const int b = m0 / TT;
        const int tb = (m0 % TT) + wr * 64;
        if (which < 2) {
            const float sc_ = (which == 0) ? QSC : 1.0f;   // pre-scale q
            unsigned short* dst = (which == 0) ? q_ws : k_ws;
            unsigned short* base = dst + (((size_t)b * HH + h) * TT) * HD;
#pragma unroll
            for (int m = 0; m < 4; ++m)
#pragma unroll
                for (int n = 0; n < 4; ++n)
#pragma unroll
                    for (int j = 0; j < 4; ++j)
                        base[(size_t)(tb + m * 16 + 4 * g + j) * HD + n * 16 + c] =
                            f2bf(acc[m][n][j] * sc_);
        } else {
            unsigned short* base = v_ws + (((size_t)b * HH + h) * HD) * TT;
#pragma unroll
            for (int m = 0; m < 4; ++m)
#pragma unroll
                for (int n = 0; n < 4; ++n)
#pragma unroll
                    for (int j = 0; j < 4; ++j)
                        base[(size_t)(n * 16 + c) * TT + tb + m * 16 + 4 * g + j] =
                            f2bf(acc[m][n][j]);
        }
    } else {
#pragma unroll
        for (int m = 0; m < 4; ++m)
#pragma unroll
            for (int n = 0; n < 4; ++n)
#pragma unroll
                for (int j = 0; j < 4; ++j)
                    outf[(size_t)(m0 + wr * 64 + m * 16 + 4 * g + j) * EE
                         + n0 + wc * 64 + n * 16 + c] = acc[m][n][j];
    }
}

// ---------------------------------------------------------------------------
// Swapped-QK^T MFMA flash attention, occupancy-targeted:
// block = (b, h, 64 q rows), 4 waves x 16 rows. Single-buffered K/V in LDS
// (18.4 KB -> 8 blocks/CU cap), reg-held prefetch across the 2 barriers,
// __launch_bounds__(256,8) pins VGPR<=64 (round-6's faster operating point).
// ---------------------------------------------------------------------------
__global__ __launch_bounds__(256, 8)
void attn_kernel(const unsigned short* __restrict__ q,
                 const unsigned short* __restrict__ k,
                 const unsigned short* __restrict__ vt,
                 unsigned short* __restrict__ attn_b) {
    __shared__ __align__(16) unsigned short Ks[64 * 72];   // [key][d]
    __shared__ __align__(16) unsigned short Vt[64 * 72];   // [d][key]

    const int qi = (TT / 64 - 1) - blockIdx.x;   // heavy blocks first
    const int h = blockIdx.y, b = blockIdx.z;
    const int tid = threadIdx.x;
    const int w = tid >> 6;
    const int lane = tid & 63;
    const int c = lane & 15;
    const int g = lane >> 4;

    const size_t head_off = (size_t)(b * HH + h) * TT * HD;
    const unsigned short* qp = q + head_off;
    const unsigned short* kp = k + head_off;
    const unsigned short* vp = vt + head_off;   // [64][T]

    const int q0w = qi * 64 + w * 16;

    const bf16x8 qa0 = *(const bf16x8*)&qp[(size_t)(q0w + c) * HD + g * 8];
    const bf16x8 qa1 = *(const bf16x8*)&qp[(size_t)(q0w + c) * HD + 32 + g * 8];

    f32x4 o[4] = {};
    float m_r = -INFINITY, l_r = 0.f;

    const int skey = tid >> 2;       // 0..63
    const int sc = tid & 3;

    const int ktiles = qi + 1;

    // prologue: tile 0 -> LDS
    {
        uint4 kA = *(const uint4*)&kp[(size_t)skey * HD + sc * 16];
        uint4 kB = *(const uint4*)&kp[(size_t)skey * HD + sc * 16 + 8];
        uint4 vA = *(const uint4*)&vp[(size_t)skey * TT + sc * 16];
        uint4 vB = *(const uint4*)&vp[(size_t)skey * TT + sc * 16 + 8];
        *(uint4*)&Ks[skey * 72 + sc * 16]     = kA;
        *(uint4*)&Ks[skey * 72 + sc * 16 + 8] = kB;
        *(uint4*)&Vt[skey * 72 + sc * 16]     = vA;
        *(uint4*)&Vt[skey * 72 + sc * 16 + 8] = vB;
    }
    __syncthreads();

    for (int kt = 0; kt < ktiles; ++kt) {
        const int kv0 = kt * 64;
        const bool last = (kt + 1 == ktiles);

        uint4 kA, kB, vA, vB;
        if (!last) {   // issue next tile's loads; latency hides under compute
            const int nv0 = kv0 + 64;
            kA = *(const uint4*)&kp[(size_t)(nv0 + skey) * HD + sc * 16];
            kB = *(const uint4*)&kp[(size_t)(nv0 + skey) * HD + sc * 16 + 8];
            vA = *(const uint4*)&vp[(size_t)skey * TT + nv0 + sc * 16];
            vB = *(const uint4*)&vp[(size_t)skey * TT + nv0 + sc * 16 + 8];
        }

        if (kv0 <= q0w + 15) {
            // ---- QK^T (swapped): s[kb] reg r = S[key=kb*16+4g+r][q=q0w+c]
            f32x4 s[4];
            __builtin_amdgcn_s_setprio(1);
#pragma unroll
            for (int kb = 0; kb < 4; ++kb) {
                const bf16x8 k0v = *(const bf16x8*)&Ks[(kb * 16 + c) * 72 + g * 8];
                const bf16x8 k1v = *(const bf16x8*)&Ks[(kb * 16 + c) * 72 + 32 + g * 8];
                f32x4 z = {0.f, 0.f, 0.f, 0.f};
                z = __builtin_amdgcn_mfma_f32_16x16x32_bf16(k0v, qa0, z, 0, 0, 0);
                s[kb] = __builtin_amdgcn_mfma_f32_16x16x32_bf16(k1v, qa1, z, 0, 0, 0);
            }
            __builtin_amdgcn_s_setprio(0);

            if (kv0 + 63 > q0w) {     // diagonal tile: causal mask
                const int rhs = q0w + c - kv0;   // key_local > rhs -> mask
#pragma unroll
                for (int kb = 0; kb < 4; ++kb)
#pragma unroll
                    for (int r = 0; r < 4; ++r)
                        if (kb * 16 + 4 * g + r > rhs) s[kb][r] = -INFINITY;
            }

            // row max: in-lane tree + 2 shfl (q = c)
            float mx;
            {
                f32x4 t0;
#pragma unroll
                for (int e = 0; e < 4; ++e)
                    t0[e] = fmaxf(fmaxf(s[0][e], s[1][e]), fmaxf(s[2][e], s[3][e]));
                mx = fmaxf(fmaxf(t0[0], t0[1]), fmaxf(t0[2], t0[3]));
            }
            mx = fmaxf(mx, __shfl_xor(mx, 16));
            mx = fmaxf(mx, __shfl_xor(mx, 32));

            const bool grow = (__all(mx <= m_r) == 0);
            float alpha = 1.f;
            if (grow) {
                const float mn = fmaxf(m_r, mx);
                alpha = exp2f(m_r - mn);
                m_r = mn;
            }

            // p = 2^(s - m); sum in-lane + 2 shfl
            float px[4][4];
#pragma unroll
            for (int kb = 0; kb < 4; ++kb)
#pragma unroll
                for (int r = 0; r < 4; ++r)
                    px[kb][r] = exp2f(s[kb][r] - m_r);
            float psum;
            {
                f32x4 a0;
#pragma unroll
                for (int e = 0; e < 4; ++e)
                    a0[e] = (px[0][e] + px[1][e]) + (px[2][e] + px[3][e]);
                psum = (a0[0] + a0[1]) + (a0[2] + a0[3]);
            }
            psum += __shfl_xor(psum, 16);
            psum += __shfl_xor(psum, 32);
            l_r = (grow ? l_r * alpha : l_r) + psum;

            if (grow) {   // alpha to o-layout (q=4g+r)
                float alo[4];
#pragma unroll
                for (int r = 0; r < 4; ++r) alo[r] = __shfl(alpha, 20 * g + r);
#pragma unroll
                for (int db = 0; db < 4; ++db)
#pragma unroll
                    for (int r = 0; r < 4; ++r) o[db][r] *= alo[r];
            }

            // pack + redistribute to PV A-frag layout
            unsigned pk[4][2];
#pragma unroll
            for (int kb = 0; kb < 4; ++kb) {
                pk[kb][0] = cvt_pk_bf16(px[kb][0], px[kb][1]);
                pk[kb][1] = cvt_pk_bf16(px[kb][2], px[kb][3]);
            }
            const int sA = c + 32 * (g & 1);
            const int sB = sA + 16;
            const bool hi = (g >= 2);
            int paw[8];
            unsigned a_, b_;
            a_ = __shfl(pk[0][0], sA); b_ = __shfl(pk[1][0], sA); paw[0] = (int)(hi ? b_ : a_);
            a_ = __shfl(pk[0][1], sA); b_ = __shfl(pk[1][1], sA); paw[1] = (int)(hi ? b_ : a_);
            a_ = __shfl(pk[0][0], sB); b_ = __shfl(pk[1][0], sB); paw[2] = (int)(hi ? b_ : a_);
            a_ = __shfl(pk[0][1], sB); b_ = __shfl(pk[1][1], sB); paw[3] = (int)(hi ? b_ : a_);
            a_ = __shfl(pk[2][0], sA); b_ = __shfl(pk[3][0], sA); paw[4] = (int)(hi ? b_ : a_);
            a_ = __shfl(pk[2][1], sA); b_ = __shfl(pk[3][1], sA); paw[5] = (int)(hi ? b_ : a_);
            a_ = __shfl(pk[2][0], sB); b_ = __shfl(pk[3][0], sB); paw[6] = (int)(hi ? b_ : a_);
            a_ = __shfl(pk[2][1], sB); b_ = __shfl(pk[3][1], sB); paw[7] = (int)(hi ? b_ : a_);

            // ---- PV: o[db] reg r = O[q=q0w+4g+r][d=db*16+c] ----
            const i32x4 w0 = {paw[0], paw[1], paw[2], paw[3]};
            const i32x4 w1 = {paw[4], paw[5], paw[6], paw[7]};
            __builtin_amdgcn_s_setprio(1);
#pragma unroll
            for (int db = 0; db < 4; ++db) {
                const bf16x8 vb0 = *(const bf16x8*)&Vt[(db * 16 + c) * 72 + g * 8];
                const bf16x8 vb1 = *(const bf16x8*)&Vt[(db * 16 + c) * 72 + 32 + g * 8];
                o[db] = __builtin_amdgcn_mfma_f32_16x16x32_bf16(
                    __builtin_bit_cast(bf16x8, w0), vb0, o[db], 0, 0, 0);
                o[db] = __builtin_amdgcn_mfma_f32_16x16x32_bf16(
                    __builtin_bit_cast(bf16x8, w1), vb1, o[db], 0, 0, 0);
            }
            __builtin_amdgcn_s_setprio(0);
        }

        __syncthreads();          // all LDS reads of tile kt done
        if (!last) {
            *(uint4*)&Ks[skey * 72 + sc * 16]     = kA;
            *(uint4*)&Ks[skey * 72 + sc * 16 + 8] = kB;
            *(uint4*)&Vt[skey * 72 + sc * 16]     = vA;
            *(uint4*)&Vt[skey * 72 + sc * 16 + 8] = vB;
        }
        __syncthreads();          // tile kt+1 visible
    }

    // epilogue: normalize (l at q=c -> shuffle to o-layout q=4g+r)
    unsigned short* op = attn_b + ((size_t)b * TT + q0w) * EE + h * HD;
    float linv[4];
#pragma unroll
    for (int r = 0; r < 4; ++r) linv[r] = 1.f / __shfl(l_r, 20 * g + r);
#pragma unroll
    for (int db = 0; db < 4; ++db)
#pragma unroll
        for (int r = 0; r < 4; ++r)
            op[(size_t)(4 * g + r) * EE + db * 16 + c] = f2bf(o[db][r] * linv[r]);
}

extern "C" void kernel_launch(void* const* d_in, const int* in_sizes, int n_in,
                              void* d_out, int out_size, void* d_ws, size_t ws_size,
                              hipStream_t stream) {
    const float* x     = (const float*)d_in[0];
    const float* wqkv  = (const float*)d_in[1];
    const float* wproj = (const float*)d_in[2];
    float* out = (float*)d_out;

    unsigned short* ws = (unsigned short*)d_ws;
    unsigned short* q_ws    = ws;                    // [B,H,T,64] (pre-scaled)
    unsigned short* k_ws    = ws + (size_t)BTE;
    unsigned short* v_ws    = ws + 2 * (size_t)BTE;  // [B,H,64,T]
    unsigned short* xb      = ws + 3 * (size_t)BTE;  // [8192][768]
    unsigned short* attn_b  = ws + 4 * (size_t)BTE;  // [8192][768]
    unsigned short* wqkv_t  = ws + 5 * (size_t)BTE;  // [2304][768]
    unsigned short* wproj_t = wqkv_t + (size_t)2304 * 768;

    convx_kernel<<<BTE / 2048, 256, 0, stream>>>(x, xb);
    transw_kernel<<<dim3(2304 / 64, KK / 64), 256, 0, stream>>>(wqkv, wqkv_t, 2304);
    transw_kernel<<<dim3(768 / 64, KK / 64), 256, 0, stream>>>(wproj, wproj_t, 768);

    mfma_gemm_kernel<0><<<dim3(2304 / 128, 8192 / 128), 256, 0, stream>>>(
        xb, wqkv_t, q_ws, k_ws, v_ws, nullptr);
    attn_kernel<<<dim3(TT / 64, HH, BB), 256, 0, stream>>>(q_ws, k_ws, v_ws, attn_b);
    mfma_gemm_kernel<1><<<dim3(EE / 128, 8192 / 128), 256, 0, stream>>>(
        attn_b, wproj_t, nullptr, nullptr, nullptr, out);
}

// Round 9
// 231.890 us; speedup vs baseline: 1.5158x; 1.5158x over previous
//
#include <hip/hip_runtime.h>
#include <hip/hip_bf16.h>

// B=4, T=2048, E=768, H=12, hd=64.
// Round 9: fragment-ordered q/k/v + global_load_lds attention.
//   - qkv GEMM epilogue writes q,k as [bh][t16][half][lane][8] and v as
//     [bh][t64][db][half][lane][8] (MFMA-fragment order, lane = g*16+c).
//   - attn: K/V staged via global_load_lds (wave-uniform dest + lane*16,
//     contiguous frag-order source), LINEAR LDS -> ds_read_b128 frag reads
//     are dense lane-linear (zero bank conflicts). Q read directly from
//     global as two 1KB coalesced bursts. 64 q rows/block (16/wave),
//     double-buffered 32KB LDS, one barrier/tile, no min-occupancy bound.

#define BB 4
#define TT 2048
#define EE 768
#define HH 12
#define HD 64
#define KK 768
#define BTE (BB*TT*EE)  // 6291456

typedef __attribute__((ext_vector_type(8))) short bf16x8;
typedef __attribute__((ext_vector_type(4))) float f32x4;
typedef __attribute__((ext_vector_type(4))) int i32x4;

#define QSC 0.18033688011112042f   // 0.125 * log2(e)

#define GLOAD16(gp, lp) \
    __builtin_amdgcn_global_load_lds( \
        (const __attribute__((address_space(1))) unsigned*)(gp), \
        (__attribute__((address_space(3))) unsigned*)(lp), 16, 0, 0)

static __device__ __forceinline__ unsigned short f2bf(float f) {
    unsigned u = __builtin_bit_cast(unsigned, f);
    u += 0x7fffu + ((u >> 16) & 1u);   // RNE
    return (unsigned short)(u >> 16);
}

static __device__ __forceinline__ unsigned cvt_pk_bf16(float lo, float hi) {
    unsigned r;
    asm("v_cvt_pk_bf16_f32 %0, %1, %2" : "=v"(r) : "v"(lo), "v"(hi));
    return r;
}

// ---------------------------------------------------------------------------
__global__ __launch_bounds__(256)
void convx_kernel(const float* __restrict__ x, unsigned short* __restrict__ xb) {
    const size_t i = ((size_t)blockIdx.x * 256 + threadIdx.x) * 8;
    float4 a = *(const float4*)&x[i];
    float4 b = *(const float4*)&x[i + 4];
    ushort4 lo, hi;
    lo.x = f2bf(a.x); lo.y = f2bf(a.y); lo.z = f2bf(a.z); lo.w = f2bf(a.w);
    hi.x = f2bf(b.x); hi.y = f2bf(b.y); hi.z = f2bf(b.z); hi.w = f2bf(b.w);
    *(ushort4*)&xb[i] = lo;
    *(ushort4*)&xb[i + 4] = hi;
}

// ---------------------------------------------------------------------------
__global__ __launch_bounds__(256)
void transw_kernel(const float* __restrict__ W, unsigned short* __restrict__ Wt, int N) {
    __shared__ unsigned short Ts[64][72];
    const int n0 = blockIdx.x * 64;
    const int k0 = blockIdx.y * 64;
    const int tid = threadIdx.x;
    {
        const int r = tid >> 4;
        const int c4 = (tid & 15) << 2;
#pragma unroll
        for (int i = 0; i < 4; ++i) {
            const int k = r + i * 16;
            float4 w4 = *(const float4*)&W[(size_t)(k0 + k) * N + n0 + c4];
            Ts[k][c4 + 0] = f2bf(w4.x); Ts[k][c4 + 1] = f2bf(w4.y);
            Ts[k][c4 + 2] = f2bf(w4.z); Ts[k][c4 + 3] = f2bf(w4.w);
        }
    }
    __syncthreads();
#pragma unroll
    for (int i = 0; i < 2; ++i) {
        const int idx = tid + i * 256;
        const int n = idx >> 3;
        const int ch = idx & 7;
        ushort4 p0, p1;
        p0.x = Ts[ch * 8 + 0][n]; p0.y = Ts[ch * 8 + 1][n];
        p0.z = Ts[ch * 8 + 2][n]; p0.w = Ts[ch * 8 + 3][n];
        p1.x = Ts[ch * 8 + 4][n]; p1.y = Ts[ch * 8 + 5][n];
        p1.z = Ts[ch * 8 + 6][n]; p1.w = Ts[ch * 8 + 7][n];
        *(ushort4*)&Wt[(size_t)(n0 + n) * KK + k0 + ch * 8] = p0;
        *(ushort4*)&Wt[(size_t)(n0 + n) * KK + k0 + ch * 8 + 4] = p1;
    }
}

// ---------------------------------------------------------------------------
// bf16 MFMA GEMM, m97-style global_load_lds staging.
// MODE 0: frag-order q/k/v epilogue. MODE 1: f32 row-major out.
// ---------------------------------------------------------------------------
template<int MODE>
__global__ __launch_bounds__(256)
void mfma_gemm_kernel(const unsigned short* __restrict__ A,
                      const unsigned short* __restrict__ Wt,
                      unsigned short* __restrict__ q_ws,
                      unsigned short* __restrict__ k_ws,
                      unsigned short* __restrict__ v_ws,
                      float* __restrict__ outf) {
    __shared__ __align__(16) unsigned short As[128 * 32];   // linear, 64B rows
    __shared__ __align__(16) unsigned short Bs[128 * 32];
    const int bx = blockIdx.x;
    const int by = blockIdx.y;
    const int tid = threadIdx.x;
    const int w = tid >> 6, lane = tid & 63;
    const int c = lane & 15, g = lane >> 4;
    const int wr = w >> 1, wc = w & 1;
    const int m0 = by * 128, n0 = bx * 128;

    const int lrow = lane >> 2;        // 0..15
    const int lch  = (lane & 3) * 8;   // shorts within 32-elem row

    const unsigned short* Ap = A  + (size_t)m0 * KK;
    const unsigned short* Bp = Wt + (size_t)n0 * KK;

    f32x4 acc[4][4] = {};

    for (int kt = 0; kt < KK / 32; ++kt) {
        const int k0 = kt * 32;
        __syncthreads();
        GLOAD16(Ap + (size_t)(w * 32 +  0 + lrow) * KK + k0 + lch, &As[(w * 32 +  0) * 32]);
        GLOAD16(Ap + (size_t)(w * 32 + 16 + lrow) * KK + k0 + lch, &As[(w * 32 + 16) * 32]);
        GLOAD16(Bp + (size_t)(w * 32 +  0 + lrow) * KK + k0 + lch, &Bs[(w * 32 +  0) * 32]);
        GLOAD16(Bp + (size_t)(w * 32 + 16 + lrow) * KK + k0 + lch, &Bs[(w * 32 + 16) * 32]);
        __syncthreads();

        bf16x8 af[4], bfr[4];
#pragma unroll
        for (int m = 0; m < 4; ++m)
            af[m] = *(const bf16x8*)&As[(wr * 64 + m * 16 + c) * 32 + g * 8];
#pragma unroll
        for (int n = 0; n < 4; ++n)
            bfr[n] = *(const bf16x8*)&Bs[(wc * 64 + n * 16 + c) * 32 + g * 8];
#pragma unroll
        for (int m = 0; m < 4; ++m)
#pragma unroll
            for (int n = 0; n < 4; ++n)
                acc[m][n] = __builtin_amdgcn_mfma_f32_16x16x32_bf16(af[m], bfr[n], acc[m][n], 0, 0, 0);
    }

    if (MODE == 0) {
        const int which = n0 / EE;
        const int hh = (n0 % EE) / HD + wc;
        const int bb = m0 / TT;
        const int tb = (m0 % TT) + wr * 64;
        const int bh = bb * HH + hh;
        if (which < 2) {
            // frag layout: [bh][t16][half][lane=gq*16+cq][8]
            const float sc_ = (which == 0) ? QSC : 1.0f;
            unsigned short* dst = (which == 0) ? q_ws : k_ws;
#pragma unroll
            for (int m = 0; m < 4; ++m) {
                const int t16 = (tb >> 4) + m;
                unsigned short* tbase = dst + (((size_t)bh * (TT / 16) + t16) * 2) * 512;
#pragma unroll
                for (int n = 0; n < 4; ++n) {
                    const int half = n >> 1;
                    const int d32 = (n & 1) * 16 + c;
                    const int gq = d32 >> 3, e = d32 & 7;
#pragma unroll
                    for (int j = 0; j < 4; ++j) {
                        const int cq = 4 * g + j;
                        tbase[(size_t)half * 512 + (gq * 16 + cq) * 8 + e] =
                            f2bf(acc[m][n][j] * sc_);
                    }
                }
            }
        } else {
            // frag layout: [bh][t64][db][half][lane=gv*16+cv][8]
            unsigned short* vb = v_ws + ((size_t)bh * (TT / 64) + (tb >> 6)) * 4096;
#pragma unroll
            for (int m = 0; m < 4; ++m)
#pragma unroll
                for (int n = 0; n < 4; ++n)
#pragma unroll
                    for (int j = 0; j < 4; ++j) {
                        const int kin = m * 16 + 4 * g + j;   // key within 64
                        const int half = kin >> 5;
                        const int gv = (kin >> 3) & 3, e = kin & 7;
                        vb[((size_t)n * 2 + half) * 512 + (gv * 16 + c) * 8 + e] =
                            f2bf(acc[m][n][j]);
                    }
        }
    } else {
#pragma unroll
        for (int m = 0; m < 4; ++m)
#pragma unroll
            for (int n = 0; n < 4; ++n)
#pragma unroll
                for (int j = 0; j < 4; ++j)
                    outf[(size_t)(m0 + wr * 64 + m * 16 + 4 * g + j) * EE
                         + n0 + wc * 64 + n * 16 + c] = acc[m][n][j];
    }
}

// ---------------------------------------------------------------------------
// Swapped-QK^T MFMA flash attention, fragment-ordered inputs.
// Block = (b,h,64 q rows), 4 waves x 16 rows. K/V staged via global_load_lds
// into linear LDS chunks (1KB per (kb|db,half)); frag ds_read_b128 are dense
// lane-linear (conflict-free). Double-buffered, one barrier per tile.
// ---------------------------------------------------------------------------
__global__ __launch_bounds__(256)
void attn_kernel(const unsigned short* __restrict__ qf,
                 const unsigned short* __restrict__ kfr,
                 const unsigned short* __restrict__ vfr,
                 unsigned short* __restrict__ attn_b) {
    __shared__ __align__(16) unsigned short Ks[2][4096];   // [kb*2+half][512]
    __shared__ __align__(16) unsigned short Vs[2][4096];   // [db*2+half][512]

    const int qi = (TT / 64 - 1) - blockIdx.x;   // heavy blocks first
    const int h = blockIdx.y, b = blockIdx.z;
    const int bh = b * HH + h;
    const int tid = threadIdx.x;
    const int w = tid >> 6;
    const int lane = tid & 63;
    const int c = lane & 15;
    const int g = lane >> 4;

    const int q0w = qi * 64 + w * 16;

    // Q frags direct from global: two coalesced 1KB bursts
    const unsigned short* qbase = qf + (((size_t)bh * (TT / 16) + (q0w >> 4)) * 2) * 512;
    const bf16x8 qa0 = *(const bf16x8*)&qbase[lane * 8];
    const bf16x8 qa1 = *(const bf16x8*)&qbase[512 + lane * 8];

    const unsigned short* kfb = kfr + ((size_t)bh * (TT / 16)) * 1024;
    const unsigned short* vfb = vfr + ((size_t)bh * (TT / 64)) * 4096;

    f32x4 o[4] = {};
    float m_r = -INFINITY, l_r = 0.f;

    const int ktiles = qi + 1;

    // wave w stages K chunks (kb=w, half=0/1) and V chunks (db=w, half=0/1)
#define STAGE(pp, kt_) do { \
        const unsigned short* ksrc = kfb + (size_t)((kt_) * 4 + w) * 1024 + lane * 8; \
        GLOAD16(ksrc,       &Ks[pp][(w * 2 + 0) * 512]); \
        GLOAD16(ksrc + 512, &Ks[pp][(w * 2 + 1) * 512]); \
        const unsigned short* vsrc = vfb + (size_t)(kt_) * 4096 + w * 1024 + lane * 8; \
        GLOAD16(vsrc,       &Vs[pp][(w * 2 + 0) * 512]); \
        GLOAD16(vsrc + 512, &Vs[pp][(w * 2 + 1) * 512]); \
    } while (0)

    STAGE(0, 0);
    __syncthreads();
    int p = 0;

    for (int kt = 0; kt < ktiles; ++kt) {
        const int kv0 = kt * 64;
        if (kt + 1 < ktiles) STAGE(p ^ 1, kt + 1);   // prefetch next tile

        if (kv0 <= q0w + 15) {
            // ---- QK^T (swapped): s[kb] reg r = S[key=kb*16+4g+r][q=q0w+c]
            f32x4 s[4];
            __builtin_amdgcn_s_setprio(1);
#pragma unroll
            for (int kb = 0; kb < 4; ++kb) {
                const bf16x8 k0v = *(const bf16x8*)&Ks[p][(kb * 2 + 0) * 512 + lane * 8];
                const bf16x8 k1v = *(const bf16x8*)&Ks[p][(kb * 2 + 1) * 512 + lane * 8];
                f32x4 z = {0.f, 0.f, 0.f, 0.f};
                z = __builtin_amdgcn_mfma_f32_16x16x32_bf16(k0v, qa0, z, 0, 0, 0);
                s[kb] = __builtin_amdgcn_mfma_f32_16x16x32_bf16(k1v, qa1, z, 0, 0, 0);
            }
            __builtin_amdgcn_s_setprio(0);

            if (kv0 + 63 > q0w) {     // diagonal tile: causal mask
                const int rhs = q0w + c - kv0;   // key_local > rhs -> mask
#pragma unroll
                for (int kb = 0; kb < 4; ++kb)
#pragma unroll
                    for (int r = 0; r < 4; ++r)
                        if (kb * 16 + 4 * g + r > rhs) s[kb][r] = -INFINITY;
            }

            // row max: in-lane tree + 2 shfl (q = c)
            float mx;
            {
                f32x4 t0;
#pragma unroll
                for (int e = 0; e < 4; ++e)
                    t0[e] = fmaxf(fmaxf(s[0][e], s[1][e]), fmaxf(s[2][e], s[3][e]));
                mx = fmaxf(fmaxf(t0[0], t0[1]), fmaxf(t0[2], t0[3]));
            }
            mx = fmaxf(mx, __shfl_xor(mx, 16));
            mx = fmaxf(mx, __shfl_xor(mx, 32));

            const bool grow = (__all(mx <= m_r) == 0);
            float alpha = 1.f;
            if (grow) {
                const float mn = fmaxf(m_r, mx);
                alpha = exp2f(m_r - mn);
                m_r = mn;
            }

            // p = 2^(s - m); sum in-lane + 2 shfl
            float px[4][4];
#pragma unroll
            for (int kb = 0; kb < 4; ++kb)
#pragma unroll
                for (int r = 0; r < 4; ++r)
                    px[kb][r] = exp2f(s[kb][r] - m_r);
            float psum;
            {
                f32x4 a0;
#pragma unroll
                for (int e = 0; e < 4; ++e)
                    a0[e] = (px[0][e] + px[1][e]) + (px[2][e] + px[3][e]);
                psum = (a0[0] + a0[1]) + (a0[2] + a0[3]);
            }
            psum += __shfl_xor(psum, 16);
            psum += __shfl_xor(psum, 32);
            l_r = (grow ? l_r * alpha : l_r) + psum;

            if (grow) {   // alpha to o-layout (q=4g+r)
                float alo[4];
#pragma unroll
                for (int r = 0; r < 4; ++r) alo[r] = __shfl(alpha, 20 * g + r);
#pragma unroll
                for (int db = 0; db < 4; ++db)
#pragma unroll
                    for (int r = 0; r < 4; ++r) o[db][r] *= alo[r];
            }

            // pack + redistribute to PV A-frag layout
            unsigned pk[4][2];
#pragma unroll
            for (int kb = 0; kb < 4; ++kb) {
                pk[kb][0] = cvt_pk_bf16(px[kb][0], px[kb][1]);
                pk[kb][1] = cvt_pk_bf16(px[kb][2], px[kb][3]);
            }
            const int sA = c + 32 * (g & 1);
            const int sB = sA + 16;
            const bool hi = (g >= 2);
            int paw[8];
            unsigned a_, b_;
            a_ = __shfl(pk[0][0], sA); b_ = __shfl(pk[1][0], sA); paw[0] = (int)(hi ? b_ : a_);
            a_ = __shfl(pk[0][1], sA); b_ = __shfl(pk[1][1], sA); paw[1] = (int)(hi ? b_ : a_);
            a_ = __shfl(pk[0][0], sB); b_ = __shfl(pk[1][0], sB); paw[2] = (int)(hi ? b_ : a_);
            a_ = __shfl(pk[0][1], sB); b_ = __shfl(pk[1][1], sB); paw[3] = (int)(hi ? b_ : a_);
            a_ = __shfl(pk[2][0], sA); b_ = __shfl(pk[3][0], sA); paw[4] = (int)(hi ? b_ : a_);
            a_ = __shfl(pk[2][1], sA); b_ = __shfl(pk[3][1], sA); paw[5] = (int)(hi ? b_ : a_);
            a_ = __shfl(pk[2][0], sB); b_ = __shfl(pk[3][0], sB); paw[6] = (int)(hi ? b_ : a_);
            a_ = __shfl(pk[2][1], sB); b_ = __shfl(pk[3][1], sB); paw[7] = (int)(hi ? b_ : a_);

            // ---- PV: o[db] reg r = O[q=q0w+4g+r][d=db*16+c] ----
            const i32x4 w0 = {paw[0], paw[1], paw[2], paw[3]};
            const i32x4 w1 = {paw[4], paw[5], paw[6], paw[7]};
            __builtin_amdgcn_s_setprio(1);
#pragma unroll
            for (int db = 0; db < 4; ++db) {
                const bf16x8 vb0 = *(const bf16x8*)&Vs[p][(db * 2 + 0) * 512 + lane * 8];
                const bf16x8 vb1 = *(const bf16x8*)&Vs[p][(db * 2 + 1) * 512 + lane * 8];
                o[db] = __builtin_amdgcn_mfma_f32_16x16x32_bf16(
                    __builtin_bit_cast(bf16x8, w0), vb0, o[db], 0, 0, 0);
                o[db] = __builtin_amdgcn_mfma_f32_16x16x32_bf16(
                    __builtin_bit_cast(bf16x8, w1), vb1, o[db], 0, 0, 0);
            }
            __builtin_amdgcn_s_setprio(0);
        }

        __syncthreads();   // all reads of buf p done; staged buf p^1 landed
        p ^= 1;
    }
#undef STAGE

    // epilogue: normalize (l at q=c -> shuffle to o-layout q=4g+r)
    unsigned short* op = attn_b + ((size_t)b * TT + q0w) * EE + h * HD;
    float linv[4];
#pragma unroll
    for (int r = 0; r < 4; ++r) linv[r] = 1.f / __shfl(l_r, 20 * g + r);
#pragma unroll
    for (int db = 0; db < 4; ++db)
#pragma unroll
        for (int r = 0; r < 4; ++r)
            op[(size_t)(4 * g + r) * EE + db * 16 + c] = f2bf(o[db][r] * linv[r]);
}

extern "C" void kernel_launch(void* const* d_in, const int* in_sizes, int n_in,
                              void* d_out, int out_size, void* d_ws, size_t ws_size,
                              hipStream_t stream) {
    const float* x     = (const float*)d_in[0];
    const float* wqkv  = (const float*)d_in[1];
    const float* wproj = (const float*)d_in[2];
    float* out = (float*)d_out;

    unsigned short* ws = (unsigned short*)d_ws;
    unsigned short* q_ws    = ws;                    // frag order (pre-scaled)
    unsigned short* k_ws    = ws + (size_t)BTE;      // frag order
    unsigned short* v_ws    = ws + 2 * (size_t)BTE;  // frag order
    unsigned short* xb      = ws + 3 * (size_t)BTE;  // [8192][768]
    unsigned short* attn_b  = ws + 4 * (size_t)BTE;  // [8192][768]
    unsigned short* wqkv_t  = ws + 5 * (size_t)BTE;  // [2304][768]
    unsigned short* wproj_t = wqkv_t + (size_t)2304 * 768;

    convx_kernel<<<BTE / 2048, 256, 0, stream>>>(x, xb);
    transw_kernel<<<dim3(2304 / 64, KK / 64), 256, 0, stream>>>(wqkv, wqkv_t, 2304);
    transw_kernel<<<dim3(768 / 64, KK / 64), 256, 0, stream>>>(wproj, wproj_t, 768);

    mfma_gemm_kernel<0><<<dim3(2304 / 128, 8192 / 128), 256, 0, stream>>>(
        xb, wqkv_t, q_ws, k_ws, v_ws, nullptr);
    attn_kernel<<<dim3(TT / 64, HH, BB), 256, 0, stream>>>(q_ws, k_ws, v_ws, attn_b);
    mfma_gemm_kernel<1><<<dim3(EE / 128, 8192 / 128), 256, 0, stream>>>(
        attn_b, wproj_t, nullptr, nullptr, nullptr, out);
}

// Round 10
// 207.341 us; speedup vs baseline: 1.6953x; 1.1184x over previous
//
#include <hip/hip_runtime.h>
#include <hip/hip_bf16.h>

// B=4, T=2048, E=768, H=12, hd=64.
// Round 10: 32x32x16 MFMA attention (m214 structure).
//   - qkv GEMM epilogue writes q,k as [bh][t32][dslice=4][lane=64][8] and
//     v as [bh][kv64][dtile=2][ks=4][lane=64][8] (32x32 frag order,
//     lane = (row&31) + 32*k-group).
//   - attn: wave owns 32 q rows; swapped QK^T (mfma(K,Q)) -> lane holds 32
//     of 64 keys for its q row; softmax = 31 VALU + 1 shfl_xor(32);
//     P->A-frag via 16 cvt_pk + 8 shfl_xor(32) + selects; defer-max
//     (THR=11.5 log2) makes o-rescale rare. K/V via global_load_lds,
//     double-buffered, one barrier/tile.

#define BB 4
#define TT 2048
#define EE 768
#define HH 12
#define HD 64
#define KK 768
#define BTE (BB*TT*EE)  // 6291456

typedef __attribute__((ext_vector_type(8))) short bf16x8;
typedef __attribute__((ext_vector_type(4))) float f32x4;
typedef __attribute__((ext_vector_type(16))) float f32x16;
typedef __attribute__((ext_vector_type(4))) int i32x4;

#define QSC 0.18033688011112042f   // 0.125 * log2(e)
#define THR2 11.5f                 // defer-max threshold (log2 units ~ e^8)

#define GLOAD16(gp, lp) \
    __builtin_amdgcn_global_load_lds( \
        (const __attribute__((address_space(1))) unsigned*)(gp), \
        (__attribute__((address_space(3))) unsigned*)(lp), 16, 0, 0)

static __device__ __forceinline__ unsigned short f2bf(float f) {
    unsigned u = __builtin_bit_cast(unsigned, f);
    u += 0x7fffu + ((u >> 16) & 1u);   // RNE
    return (unsigned short)(u >> 16);
}

static __device__ __forceinline__ unsigned cvt_pk_bf16(float lo, float hi) {
    unsigned r;
    asm("v_cvt_pk_bf16_f32 %0, %1, %2" : "=v"(r) : "v"(lo), "v"(hi));
    return r;
}

// ---------------------------------------------------------------------------
__global__ __launch_bounds__(256)
void convx_kernel(const float* __restrict__ x, unsigned short* __restrict__ xb) {
    const size_t i = ((size_t)blockIdx.x * 256 + threadIdx.x) * 8;
    float4 a = *(const float4*)&x[i];
    float4 b = *(const float4*)&x[i + 4];
    ushort4 lo, hi;
    lo.x = f2bf(a.x); lo.y = f2bf(a.y); lo.z = f2bf(a.z); lo.w = f2bf(a.w);
    hi.x = f2bf(b.x); hi.y = f2bf(b.y); hi.z = f2bf(b.z); hi.w = f2bf(b.w);
    *(ushort4*)&xb[i] = lo;
    *(ushort4*)&xb[i + 4] = hi;
}

// ---------------------------------------------------------------------------
__global__ __launch_bounds__(256)
void transw_kernel(const float* __restrict__ W, unsigned short* __restrict__ Wt, int N) {
    __shared__ unsigned short Ts[64][72];
    const int n0 = blockIdx.x * 64;
    const int k0 = blockIdx.y * 64;
    const int tid = threadIdx.x;
    {
        const int r = tid >> 4;
        const int c4 = (tid & 15) << 2;
#pragma unroll
        for (int i = 0; i < 4; ++i) {
            const int k = r + i * 16;
            float4 w4 = *(const float4*)&W[(size_t)(k0 + k) * N + n0 + c4];
            Ts[k][c4 + 0] = f2bf(w4.x); Ts[k][c4 + 1] = f2bf(w4.y);
            Ts[k][c4 + 2] = f2bf(w4.z); Ts[k][c4 + 3] = f2bf(w4.w);
        }
    }
    __syncthreads();
#pragma unroll
    for (int i = 0; i < 2; ++i) {
        const int idx = tid + i * 256;
        const int n = idx >> 3;
        const int ch = idx & 7;
        ushort4 p0, p1;
        p0.x = Ts[ch * 8 + 0][n]; p0.y = Ts[ch * 8 + 1][n];
        p0.z = Ts[ch * 8 + 2][n]; p0.w = Ts[ch * 8 + 3][n];
        p1.x = Ts[ch * 8 + 4][n]; p1.y = Ts[ch * 8 + 5][n];
        p1.z = Ts[ch * 8 + 6][n]; p1.w = Ts[ch * 8 + 7][n];
        *(ushort4*)&Wt[(size_t)(n0 + n) * KK + k0 + ch * 8] = p0;
        *(ushort4*)&Wt[(size_t)(n0 + n) * KK + k0 + ch * 8 + 4] = p1;
    }
}

// ---------------------------------------------------------------------------
// bf16 MFMA GEMM, m97-style global_load_lds staging.
// MODE 0: 32x32-frag-order q/k/v epilogue. MODE 1: f32 row-major out.
// ---------------------------------------------------------------------------
template<int MODE>
__global__ __launch_bounds__(256)
void mfma_gemm_kernel(const unsigned short* __restrict__ A,
                      const unsigned short* __restrict__ Wt,
                      unsigned short* __restrict__ q_ws,
                      unsigned short* __restrict__ k_ws,
                      unsigned short* __restrict__ v_ws,
                      float* __restrict__ outf) {
    __shared__ __align__(16) unsigned short As[128 * 32];   // linear, 64B rows
    __shared__ __align__(16) unsigned short Bs[128 * 32];
    const int bx = blockIdx.x;
    const int by = blockIdx.y;
    const int tid = threadIdx.x;
    const int w = tid >> 6, lane = tid & 63;
    const int c = lane & 15, g = lane >> 4;
    const int wr = w >> 1, wc = w & 1;
    const int m0 = by * 128, n0 = bx * 128;

    const int lrow = lane >> 2;        // 0..15
    const int lch  = (lane & 3) * 8;   // shorts within 32-elem row

    const unsigned short* Ap = A  + (size_t)m0 * KK;
    const unsigned short* Bp = Wt + (size_t)n0 * KK;

    f32x4 acc[4][4] = {};

    for (int kt = 0; kt < KK / 32; ++kt) {
        const int k0 = kt * 32;
        __syncthreads();
        GLOAD16(Ap + (size_t)(w * 32 +  0 + lrow) * KK + k0 + lch, &As[(w * 32 +  0) * 32]);
        GLOAD16(Ap + (size_t)(w * 32 + 16 + lrow) * KK + k0 + lch, &As[(w * 32 + 16) * 32]);
        GLOAD16(Bp + (size_t)(w * 32 +  0 + lrow) * KK + k0 + lch, &Bs[(w * 32 +  0) * 32]);
        GLOAD16(Bp + (size_t)(w * 32 + 16 + lrow) * KK + k0 + lch, &Bs[(w * 32 + 16) * 32]);
        __syncthreads();

        bf16x8 af[4], bfr[4];
#pragma unroll
        for (int m = 0; m < 4; ++m)
            af[m] = *(const bf16x8*)&As[(wr * 64 + m * 16 + c) * 32 + g * 8];
#pragma unroll
        for (int n = 0; n < 4; ++n)
            bfr[n] = *(const bf16x8*)&Bs[(wc * 64 + n * 16 + c) * 32 + g * 8];
#pragma unroll
        for (int m = 0; m < 4; ++m)
#pragma unroll
            for (int n = 0; n < 4; ++n)
                acc[m][n] = __builtin_amdgcn_mfma_f32_16x16x32_bf16(af[m], bfr[n], acc[m][n], 0, 0, 0);
    }

    if (MODE == 0) {
        // GEMM output element: row t = tb + m*16 + 4g + j, col d = n*16 + c
        const int which = n0 / EE;
        const int hh = (n0 % EE) / HD + wc;
        const int bb = m0 / TT;
        const int tb = (m0 % TT) + wr * 64;
        const int bh = bb * HH + hh;
        if (which < 2) {
            // q/k frag: addr = ((bh*(T/32) + t>>5)*4 + d>>4)*512
            //                + ((t&31) + 32*((d>>3)&1))*8 + (d&7)
            const float sc_ = (which == 0) ? QSC : 1.0f;
            unsigned short* dst = (which == 0) ? q_ws : k_ws;
#pragma unroll
            for (int m = 0; m < 4; ++m) {
                const int t32 = (tb >> 5) + (m >> 1);
#pragma unroll
                for (int n = 0; n < 4; ++n) {
                    unsigned short* base = dst
                        + ((size_t)(bh * (TT / 32) + t32) * 4 + n) * 512
                        + ((m & 1) * 16 + 4 * g + 32 * (c >> 3)) * 8 + (c & 7);
#pragma unroll
                    for (int j = 0; j < 4; ++j)
                        base[j * 8] = f2bf(acc[m][n][j] * sc_);
                }
            }
        } else {
            // v frag: chunk = (bh*(T/64) + t>>6)*8 + (d>>5)*4 + ((t&63)>>4)
            //         lane = (d&31) + 32*((t>>3)&1), e = t&7
            unsigned short* vb = v_ws + ((size_t)(bh * (TT / 64) + (tb >> 6))) * 4096;
#pragma unroll
            for (int m = 0; m < 4; ++m)
#pragma unroll
                for (int n = 0; n < 4; ++n) {
                    unsigned short* base = vb + ((size_t)(n >> 1) * 4 + m) * 512
                        + ((n & 1) * 16 + c + 32 * (g >> 1)) * 8 + 4 * (g & 1);
                    ushort4 pk;
                    pk.x = f2bf(acc[m][n][0]); pk.y = f2bf(acc[m][n][1]);
                    pk.z = f2bf(acc[m][n][2]); pk.w = f2bf(acc[m][n][3]);
                    *(ushort4*)base = pk;
                }
        }
    } else {
#pragma unroll
        for (int m = 0; m < 4; ++m)
#pragma unroll
            for (int n = 0; n < 4; ++n)
#pragma unroll
                for (int j = 0; j < 4; ++j)
                    outf[(size_t)(m0 + wr * 64 + m * 16 + 4 * g + j) * EE
                         + n0 + wc * 64 + n * 16 + c] = acc[m][n][j];
    }
}

// ---------------------------------------------------------------------------
// 32x32 swapped-QK^T MFMA flash attention.
// Block = (b, h, 128 q rows), 4 waves x 32 rows. KVBLK=64.
// S = mfma(K,Q): lane l holds S[key = kv0 + kb*32 + crow(r,hi)][q = q0w+(l&31)]
// where crow(r,hi) = (r&3)+8*(r>>2)+4*hi, hi = l>>5. Lane pair (l, l^32)
// holds the full 64-key row -> softmax = in-lane tree + 1 shfl_xor(32).
// ---------------------------------------------------------------------------
__global__ __launch_bounds__(256)
void attn_kernel(const unsigned short* __restrict__ qf,
                 const unsigned short* __restrict__ kfr,
                 const unsigned short* __restrict__ vfr,
                 unsigned short* __restrict__ attn_b) {
    __shared__ __align__(16) unsigned short Ks[2][8 * 512];   // [kb32*4+ds][512]
    __shared__ __align__(16) unsigned short Vs[2][8 * 512];   // [dt*4+ks][512]

    const int qi = (TT / 128 - 1) - blockIdx.x;   // heavy blocks first
    const int h = blockIdx.y, b = blockIdx.z;
    const int bh = b * HH + h;
    const int tid = threadIdx.x;
    const int w = tid >> 6;
    const int lane = tid & 63;
    const int lq = lane & 31;
    const int hiL = lane >> 5;

    const int q0w = qi * 128 + w * 32;
    const int qg = q0w + lq;                      // this lane's q row

    // Q B-frags: lane l holds Q[q0w + (l&31)][d = ds*16 + (l>>5)*8 + e]
    const unsigned short* qbase = qf + ((size_t)(bh * (TT / 32) + qi * 4 + w)) * 2048;
    bf16x8 qa[4];
#pragma unroll
    for (int ds = 0; ds < 4; ++ds)
        qa[ds] = *(const bf16x8*)&qbase[ds * 512 + lane * 8];

    const unsigned short* kfb = kfr + (size_t)bh * 131072;
    const unsigned short* vfb = vfr + (size_t)bh * 131072;

    f32x16 o0 = {}, o1 = {};      // O[q=crow(r,hi)][d=lq] , d+32
    float m_r = -INFINITY, l_r = 0.f;

    const int ktiles = 2 * qi + 2;

    // waves 0,1 stage K (kb32 = w); waves 2,3 stage V (dt = w-2)
#define STAGE(pp, kt_) do { \
        if (w < 2) { \
            const unsigned short* ks_ = kfb + ((size_t)((kt_) * 2 + w) * 4) * 512 + lane * 8; \
            GLOAD16(ks_,        &Ks[pp][(w * 4 + 0) * 512]); \
            GLOAD16(ks_ +  512, &Ks[pp][(w * 4 + 1) * 512]); \
            GLOAD16(ks_ + 1024, &Ks[pp][(w * 4 + 2) * 512]); \
            GLOAD16(ks_ + 1536, &Ks[pp][(w * 4 + 3) * 512]); \
        } else { \
            const int dt_ = w - 2; \
            const unsigned short* vs_ = vfb + ((size_t)(kt_) * 8 + dt_ * 4) * 512 + lane * 8; \
            GLOAD16(vs_,        &Vs[pp][(dt_ * 4 + 0) * 512]); \
            GLOAD16(vs_ +  512, &Vs[pp][(dt_ * 4 + 1) * 512]); \
            GLOAD16(vs_ + 1024, &Vs[pp][(dt_ * 4 + 2) * 512]); \
            GLOAD16(vs_ + 1536, &Vs[pp][(dt_ * 4 + 3) * 512]); \
        } } while (0)

    STAGE(0, 0);
    __syncthreads();
    int p = 0;

    for (int kt = 0; kt < ktiles; ++kt) {
        const int kv0 = kt * 64;
        if (kt + 1 < ktiles) STAGE(p ^ 1, kt + 1);

        if (kv0 <= q0w + 31) {
            // ---- QK^T: two 32x32 S tiles ----
            f32x16 s0 = {}, s1 = {};
            __builtin_amdgcn_s_setprio(1);
#pragma unroll
            for (int ds = 0; ds < 4; ++ds) {
                const bf16x8 kf0 = *(const bf16x8*)&Ks[p][(0 + ds) * 512 + lane * 8];
                const bf16x8 kf1 = *(const bf16x8*)&Ks[p][(4 + ds) * 512 + lane * 8];
                s0 = __builtin_amdgcn_mfma_f32_32x32x16_bf16(kf0, qa[ds], s0, 0, 0, 0);
                s1 = __builtin_amdgcn_mfma_f32_32x32x16_bf16(kf1, qa[ds], s1, 0, 0, 0);
            }
            __builtin_amdgcn_s_setprio(0);

            float p32[32];
#pragma unroll
            for (int r = 0; r < 16; ++r) { p32[r] = s0[r]; p32[16 + r] = s1[r]; }

            if (kv0 + 63 > q0w) {   // diagonal region: causal mask
#pragma unroll
                for (int r = 0; r < 16; ++r) {
                    const int crow = (r & 3) + 8 * (r >> 2) + 4 * hiL;
                    if (kv0 + crow > qg)      p32[r]      = -INFINITY;
                    if (kv0 + 32 + crow > qg) p32[16 + r] = -INFINITY;
                }
            }

            // row max: 31 in-lane + 1 cross-half shfl
            float mx = p32[0];
#pragma unroll
            for (int r = 1; r < 32; ++r) mx = fmaxf(mx, p32[r]);
            mx = fmaxf(mx, __shfl_xor(mx, 32));

            if (!__all(mx <= m_r + THR2)) {     // defer-max: rescale rarely
                const float mn = fmaxf(m_r, mx);
                const float alpha = exp2f(m_r - mn);
                m_r = mn;
                l_r *= alpha;
#pragma unroll
                for (int r = 0; r < 16; ++r) {
                    const float al = __shfl(alpha, (r & 3) + 8 * (r >> 2) + 4 * hiL);
                    o0[r] *= al; o1[r] *= al;
                }
            }

            // p = 2^(s - m); sum 31 in-lane + 1 shfl
            float psum = 0.f;
#pragma unroll
            for (int r = 0; r < 32; ++r) {
                p32[r] = exp2f(p32[r] - m_r);
                psum += p32[r];
            }
            psum += __shfl_xor(psum, 32);
            l_r += psum;

            // ---- PV: assemble A-frags (16 cvt_pk + 8 shfl_xor32 + selects)
            __builtin_amdgcn_s_setprio(1);
#pragma unroll
            for (int ks = 0; ks < 4; ++ks) {
                const unsigned wlo0 = cvt_pk_bf16(p32[8 * ks + 0], p32[8 * ks + 1]);
                const unsigned wlo1 = cvt_pk_bf16(p32[8 * ks + 2], p32[8 * ks + 3]);
                const unsigned whi0 = cvt_pk_bf16(p32[8 * ks + 4], p32[8 * ks + 5]);
                const unsigned whi1 = cvt_pk_bf16(p32[8 * ks + 6], p32[8 * ks + 7]);
                const unsigned g0 = (unsigned)__shfl_xor((int)(hiL ? wlo0 : whi0), 32);
                const unsigned g1 = (unsigned)__shfl_xor((int)(hiL ? wlo1 : whi1), 32);
                i32x4 pw;
                pw[0] = (int)(hiL ? g0 : wlo0);
                pw[1] = (int)(hiL ? g1 : wlo1);
                pw[2] = (int)(hiL ? whi0 : g0);
                pw[3] = (int)(hiL ? whi1 : g1);
                const bf16x8 pa = __builtin_bit_cast(bf16x8, pw);
                const bf16x8 vb0 = *(const bf16x8*)&Vs[p][(0 + ks) * 512 + lane * 8];
                const bf16x8 vb1 = *(const bf16x8*)&Vs[p][(4 + ks) * 512 + lane * 8];
                o0 = __builtin_amdgcn_mfma_f32_32x32x16_bf16(pa, vb0, o0, 0, 0, 0);
                o1 = __builtin_amdgcn_mfma_f32_32x32x16_bf16(pa, vb1, o1, 0, 0, 0);
            }
            __builtin_amdgcn_s_setprio(0);
        }

        __syncthreads();   // reads of buf p done; staged buf p^1 landed
        p ^= 1;
    }
#undef STAGE

    // epilogue: O[q=crow(r,hi)][d] / l[q]
    unsigned short* op = attn_b + ((size_t)b * TT + q0w) * EE + h * HD;
#pragma unroll
    for (int r = 0; r < 16; ++r) {
        const int crow = (r & 3) + 8 * (r >> 2) + 4 * hiL;
        const float li = 1.f / __shfl(l_r, crow);
        op[(size_t)crow * EE + lq]      = f2bf(o0[r] * li);
        op[(size_t)crow * EE + 32 + lq] = f2bf(o1[r] * li);
    }
}

extern "C" void kernel_launch(void* const* d_in, const int* in_sizes, int n_in,
                              void* d_out, int out_size, void* d_ws, size_t ws_size,
                              hipStream_t stream) {
    const float* x     = (const float*)d_in[0];
    const float* wqkv  = (const float*)d_in[1];
    const float* wproj = (const float*)d_in[2];
    float* out = (float*)d_out;

    unsigned short* ws = (unsigned short*)d_ws;
    unsigned short* q_ws    = ws;                    // 32x32 frag order (pre-scaled)
    unsigned short* k_ws    = ws + (size_t)BTE;      // frag order
    unsigned short* v_ws    = ws + 2 * (size_t)BTE;  // frag order
    unsigned short* xb      = ws + 3 * (size_t)BTE;  // [8192][768]
    unsigned short* attn_b  = ws + 4 * (size_t)BTE;  // [8192][768]
    unsigned short* wqkv_t  = ws + 5 * (size_t)BTE;  // [2304][768]
    unsigned short* wproj_t = wqkv_t + (size_t)2304 * 768;

    convx_kernel<<<BTE / 2048, 256, 0, stream>>>(x, xb);
    transw_kernel<<<dim3(2304 / 64, KK / 64), 256, 0, stream>>>(wqkv, wqkv_t, 2304);
    transw_kernel<<<dim3(768 / 64, KK / 64), 256, 0, stream>>>(wproj, wproj_t, 768);

    mfma_gemm_kernel<0><<<dim3(2304 / 128, 8192 / 128), 256, 0, stream>>>(
        xb, wqkv_t, q_ws, k_ws, v_ws, nullptr);
    attn_kernel<<<dim3(TT / 128, HH, BB), 256, 0, stream>>>(q_ws, k_ws, v_ws, attn_b);
    mfma_gemm_kernel<1><<<dim3(EE / 128, 8192 / 128), 256, 0, stream>>>(
        attn_b, wproj_t, nullptr, nullptr, nullptr, out);
}

// Round 11
// 153.569 us; speedup vs baseline: 2.2889x; 1.3502x over previous
//
#include <hip/hip_runtime.h>
#include <hip/hip_bf16.h>

// B=4, T=2048, E=768, H=12, hd=64.
// Round 11: barrier-free attention. 1 wave / block (32 q rows), K/V/Q
// fragments loaded DIRECTLY global->registers (lane-linear 1KB bursts,
// frag-ordered by the qkv GEMM epilogue). No LDS, no __syncthreads.
// 3072 equal-dispatch-cost-ordered blocks (LPT: heavy q-tiles first across
// all heads) -> ~12 blocks/CU backfill, ~3 waves/SIMD latency hiding.
// Balanced max/sum trees (depth 5) replace 31-deep dependent chains.

#define BB 4
#define TT 2048
#define EE 768
#define HH 12
#define HD 64
#define KK 768
#define BTE (BB*TT*EE)  // 6291456

typedef __attribute__((ext_vector_type(8))) short bf16x8;
typedef __attribute__((ext_vector_type(4))) float f32x4;
typedef __attribute__((ext_vector_type(16))) float f32x16;
typedef __attribute__((ext_vector_type(4))) int i32x4;

#define QSC 0.18033688011112042f   // 0.125 * log2(e)
#define THR2 11.5f                 // defer-max threshold (log2 units ~ e^8)

#define GLOAD16(gp, lp) \
    __builtin_amdgcn_global_load_lds( \
        (const __attribute__((address_space(1))) unsigned*)(gp), \
        (__attribute__((address_space(3))) unsigned*)(lp), 16, 0, 0)

static __device__ __forceinline__ unsigned short f2bf(float f) {
    unsigned u = __builtin_bit_cast(unsigned, f);
    u += 0x7fffu + ((u >> 16) & 1u);   // RNE
    return (unsigned short)(u >> 16);
}

static __device__ __forceinline__ unsigned cvt_pk_bf16(float lo, float hi) {
    unsigned r;
    asm("v_cvt_pk_bf16_f32 %0, %1, %2" : "=v"(r) : "v"(lo), "v"(hi));
    return r;
}

// ---------------------------------------------------------------------------
__global__ __launch_bounds__(256)
void convx_kernel(const float* __restrict__ x, unsigned short* __restrict__ xb) {
    const size_t i = ((size_t)blockIdx.x * 256 + threadIdx.x) * 8;
    float4 a = *(const float4*)&x[i];
    float4 b = *(const float4*)&x[i + 4];
    ushort4 lo, hi;
    lo.x = f2bf(a.x); lo.y = f2bf(a.y); lo.z = f2bf(a.z); lo.w = f2bf(a.w);
    hi.x = f2bf(b.x); hi.y = f2bf(b.y); hi.z = f2bf(b.z); hi.w = f2bf(b.w);
    *(ushort4*)&xb[i] = lo;
    *(ushort4*)&xb[i + 4] = hi;
}

// ---------------------------------------------------------------------------
__global__ __launch_bounds__(256)
void transw_kernel(const float* __restrict__ W, unsigned short* __restrict__ Wt, int N) {
    __shared__ unsigned short Ts[64][72];
    const int n0 = blockIdx.x * 64;
    const int k0 = blockIdx.y * 64;
    const int tid = threadIdx.x;
    {
        const int r = tid >> 4;
        const int c4 = (tid & 15) << 2;
#pragma unroll
        for (int i = 0; i < 4; ++i) {
            const int k = r + i * 16;
            float4 w4 = *(const float4*)&W[(size_t)(k0 + k) * N + n0 + c4];
            Ts[k][c4 + 0] = f2bf(w4.x); Ts[k][c4 + 1] = f2bf(w4.y);
            Ts[k][c4 + 2] = f2bf(w4.z); Ts[k][c4 + 3] = f2bf(w4.w);
        }
    }
    __syncthreads();
#pragma unroll
    for (int i = 0; i < 2; ++i) {
        const int idx = tid + i * 256;
        const int n = idx >> 3;
        const int ch = idx & 7;
        ushort4 p0, p1;
        p0.x = Ts[ch * 8 + 0][n]; p0.y = Ts[ch * 8 + 1][n];
        p0.z = Ts[ch * 8 + 2][n]; p0.w = Ts[ch * 8 + 3][n];
        p1.x = Ts[ch * 8 + 4][n]; p1.y = Ts[ch * 8 + 5][n];
        p1.z = Ts[ch * 8 + 6][n]; p1.w = Ts[ch * 8 + 7][n];
        *(ushort4*)&Wt[(size_t)(n0 + n) * KK + k0 + ch * 8] = p0;
        *(ushort4*)&Wt[(size_t)(n0 + n) * KK + k0 + ch * 8 + 4] = p1;
    }
}

// ---------------------------------------------------------------------------
// bf16 MFMA GEMM, m97-style global_load_lds staging (unchanged from r10).
// MODE 0: 32x32-frag-order q/k/v epilogue. MODE 1: f32 row-major out.
// ---------------------------------------------------------------------------
template<int MODE>
__global__ __launch_bounds__(256)
void mfma_gemm_kernel(const unsigned short* __restrict__ A,
                      const unsigned short* __restrict__ Wt,
                      unsigned short* __restrict__ q_ws,
                      unsigned short* __restrict__ k_ws,
                      unsigned short* __restrict__ v_ws,
                      float* __restrict__ outf) {
    __shared__ __align__(16) unsigned short As[128 * 32];   // linear, 64B rows
    __shared__ __align__(16) unsigned short Bs[128 * 32];
    const int bx = blockIdx.x;
    const int by = blockIdx.y;
    const int tid = threadIdx.x;
    const int w = tid >> 6, lane = tid & 63;
    const int c = lane & 15, g = lane >> 4;
    const int wr = w >> 1, wc = w & 1;
    const int m0 = by * 128, n0 = bx * 128;

    const int lrow = lane >> 2;        // 0..15
    const int lch  = (lane & 3) * 8;   // shorts within 32-elem row

    const unsigned short* Ap = A  + (size_t)m0 * KK;
    const unsigned short* Bp = Wt + (size_t)n0 * KK;

    f32x4 acc[4][4] = {};

    for (int kt = 0; kt < KK / 32; ++kt) {
        const int k0 = kt * 32;
        __syncthreads();
        GLOAD16(Ap + (size_t)(w * 32 +  0 + lrow) * KK + k0 + lch, &As[(w * 32 +  0) * 32]);
        GLOAD16(Ap + (size_t)(w * 32 + 16 + lrow) * KK + k0 + lch, &As[(w * 32 + 16) * 32]);
        GLOAD16(Bp + (size_t)(w * 32 +  0 + lrow) * KK + k0 + lch, &Bs[(w * 32 +  0) * 32]);
        GLOAD16(Bp + (size_t)(w * 32 + 16 + lrow) * KK + k0 + lch, &Bs[(w * 32 + 16) * 32]);
        __syncthreads();

        bf16x8 af[4], bfr[4];
#pragma unroll
        for (int m = 0; m < 4; ++m)
            af[m] = *(const bf16x8*)&As[(wr * 64 + m * 16 + c) * 32 + g * 8];
#pragma unroll
        for (int n = 0; n < 4; ++n)
            bfr[n] = *(const bf16x8*)&Bs[(wc * 64 + n * 16 + c) * 32 + g * 8];
#pragma unroll
        for (int m = 0; m < 4; ++m)
#pragma unroll
            for (int n = 0; n < 4; ++n)
                acc[m][n] = __builtin_amdgcn_mfma_f32_16x16x32_bf16(af[m], bfr[n], acc[m][n], 0, 0, 0);
    }

    if (MODE == 0) {
        // GEMM output element: row t = tb + m*16 + 4g + j, col d = n*16 + c
        const int which = n0 / EE;
        const int hh = (n0 % EE) / HD + wc;
        const int bb = m0 / TT;
        const int tb = (m0 % TT) + wr * 64;
        const int bh = bb * HH + hh;
        if (which < 2) {
            // q/k frag: addr = ((bh*(T/32) + t>>5)*4 + d>>4)*512
            //                + ((t&31) + 32*((d>>3)&1))*8 + (d&7)
            const float sc_ = (which == 0) ? QSC : 1.0f;
            unsigned short* dst = (which == 0) ? q_ws : k_ws;
#pragma unroll
            for (int m = 0; m < 4; ++m) {
                const int t32 = (tb >> 5) + (m >> 1);
#pragma unroll
                for (int n = 0; n < 4; ++n) {
                    unsigned short* base = dst
                        + ((size_t)(bh * (TT / 32) + t32) * 4 + n) * 512
                        + ((m & 1) * 16 + 4 * g + 32 * (c >> 3)) * 8 + (c & 7);
#pragma unroll
                    for (int j = 0; j < 4; ++j)
                        base[j * 8] = f2bf(acc[m][n][j] * sc_);
                }
            }
        } else {
            // v frag: chunk = (bh*(T/64) + t>>6)*8 + (d>>5)*4 + ((t&63)>>4)
            //         lane = (d&31) + 32*((t>>3)&1), e = t&7
            unsigned short* vb = v_ws + ((size_t)(bh * (TT / 64) + (tb >> 6))) * 4096;
#pragma unroll
            for (int m = 0; m < 4; ++m)
#pragma unroll
                for (int n = 0; n < 4; ++n) {
                    unsigned short* base = vb + ((size_t)(n >> 1) * 4 + m) * 512
                        + ((n & 1) * 16 + c + 32 * (g >> 1)) * 8 + 4 * (g & 1);
                    ushort4 pk;
                    pk.x = f2bf(acc[m][n][0]); pk.y = f2bf(acc[m][n][1]);
                    pk.z = f2bf(acc[m][n][2]); pk.w = f2bf(acc[m][n][3]);
                    *(ushort4*)base = pk;
                }
        }
    } else {
#pragma unroll
        for (int m = 0; m < 4; ++m)
#pragma unroll
            for (int n = 0; n < 4; ++n)
#pragma unroll
                for (int j = 0; j < 4; ++j)
                    outf[(size_t)(m0 + wr * 64 + m * 16 + 4 * g + j) * EE
                         + n0 + wc * 64 + n * 16 + c] = acc[m][n][j];
    }
}

// ---------------------------------------------------------------------------
// Barrier-free 32x32 swapped-QK^T flash attention. 1 wave per block,
// 32 q rows. K/V frags loaded straight global->reg (lane-linear, coalesced).
// Grid (bh=48, qrev=64): dispatch order is heavy-first across all heads.
// ---------------------------------------------------------------------------
__global__ __launch_bounds__(64)
void attn_kernel(const unsigned short* __restrict__ qf,
                 const unsigned short* __restrict__ kfr,
                 const unsigned short* __restrict__ vfr,
                 unsigned short* __restrict__ attn_b) {
    const int bh = blockIdx.x;
    const int j = (TT / 32 - 1) - (int)blockIdx.y;   // heavy q-tiles first
    const int b = bh / HH, h = bh % HH;
    const int lane = threadIdx.x;
    const int lq = lane & 31;
    const int hiL = lane >> 5;

    const int q0 = j * 32;
    const int qg = q0 + lq;

    // Q B-frags: lane holds Q[q0 + lq][d = ds*16 + hiL*8 + e]
    const unsigned short* qbase = qf + ((size_t)(bh * (TT / 32) + j)) * 2048;
    bf16x8 qa[4];
#pragma unroll
    for (int ds = 0; ds < 4; ++ds)
        qa[ds] = *(const bf16x8*)&qbase[ds * 512 + lane * 8];

    const unsigned short* kfb = kfr + (size_t)bh * 131072;   // [t32][ds][lane][8]
    const unsigned short* vfb = vfr + (size_t)bh * 131072;   // [kv64][dt*4+ks][lane][8]

    f32x16 o0 = {}, o1 = {};      // O[q=crow(r,hi)][d=lq], d+32
    float m_r = -INFINITY, l_r = 0.f;

    const int ktiles = (j >> 1) + 1;

    for (int kt = 0; kt < ktiles; ++kt) {
        const int kv0 = kt * 64;

        // K frags (2 key-halves x 4 d-slices) + V frags (2 d-tiles x 4 k-slots)
        bf16x8 kf[8], vf[8];
        {
            const unsigned short* kc = kfb + ((size_t)(2 * kt) * 4) * 512 + lane * 8;
#pragma unroll
            for (int ch = 0; ch < 8; ++ch)
                kf[ch] = *(const bf16x8*)&kc[ch * 512];
            const unsigned short* vc = vfb + (size_t)kt * 4096 + lane * 8;
#pragma unroll
            for (int ch = 0; ch < 8; ++ch)
                vf[ch] = *(const bf16x8*)&vc[ch * 512];
        }

        // ---- QK^T: two 32x32 S tiles ----
        f32x16 s0 = {}, s1 = {};
        __builtin_amdgcn_s_setprio(1);
#pragma unroll
        for (int ds = 0; ds < 4; ++ds) {
            s0 = __builtin_amdgcn_mfma_f32_32x32x16_bf16(kf[ds],     qa[ds], s0, 0, 0, 0);
            s1 = __builtin_amdgcn_mfma_f32_32x32x16_bf16(kf[4 + ds], qa[ds], s1, 0, 0, 0);
        }
        __builtin_amdgcn_s_setprio(0);

        float p32[32];
#pragma unroll
        for (int r = 0; r < 16; ++r) { p32[r] = s0[r]; p32[16 + r] = s1[r]; }

        if (kv0 + 63 > q0) {   // diagonal region: causal mask
#pragma unroll
            for (int r = 0; r < 16; ++r) {
                const int crow = (r & 3) + 8 * (r >> 2) + 4 * hiL;
                if (kv0 + crow > qg)      p32[r]      = -INFINITY;
                if (kv0 + 32 + crow > qg) p32[16 + r] = -INFINITY;
            }
        }

        // row max: balanced tree (depth 5) + 1 cross-half shfl
        float tm[16];
#pragma unroll
        for (int r = 0; r < 16; ++r) tm[r] = fmaxf(p32[r], p32[16 + r]);
#pragma unroll
        for (int st = 8; st > 0; st >>= 1)
#pragma unroll
            for (int r = 0; r < 8; ++r)
                if (r < st) tm[r] = fmaxf(tm[r], tm[r + st]);
        float mx = fmaxf(tm[0], __shfl_xor(tm[0], 32));

        if (!__all(mx <= m_r + THR2)) {     // defer-max: rescale rarely
            const float mn = fmaxf(m_r, mx);
            const float alpha = exp2f(m_r - mn);
            m_r = mn;
            l_r *= alpha;
#pragma unroll
            for (int r = 0; r < 16; ++r) {
                const float al = __shfl(alpha, (r & 3) + 8 * (r >> 2) + 4 * hiL);
                o0[r] *= al; o1[r] *= al;
            }
        }

        // p = 2^(s - m); balanced sum tree + 1 shfl
#pragma unroll
        for (int r = 0; r < 32; ++r) p32[r] = exp2f(p32[r] - m_r);
        float ta[16];
#pragma unroll
        for (int r = 0; r < 16; ++r) ta[r] = p32[r] + p32[16 + r];
#pragma unroll
        for (int st = 8; st > 0; st >>= 1)
#pragma unroll
            for (int r = 0; r < 8; ++r)
                if (r < st) ta[r] += ta[r + st];
        l_r += ta[0] + __shfl_xor(ta[0], 32);

        // ---- PV: assemble A-frags (16 cvt_pk + 8 shfl_xor32 + selects) ----
        __builtin_amdgcn_s_setprio(1);
#pragma unroll
        for (int ks = 0; ks < 4; ++ks) {
            const unsigned wlo0 = cvt_pk_bf16(p32[8 * ks + 0], p32[8 * ks + 1]);
            const unsigned wlo1 = cvt_pk_bf16(p32[8 * ks + 2], p32[8 * ks + 3]);
            const unsigned whi0 = cvt_pk_bf16(p32[8 * ks + 4], p32[8 * ks + 5]);
            const unsigned whi1 = cvt_pk_bf16(p32[8 * ks + 6], p32[8 * ks + 7]);
            const unsigned g0 = (unsigned)__shfl_xor((int)(hiL ? wlo0 : whi0), 32);
            const unsigned g1 = (unsigned)__shfl_xor((int)(hiL ? wlo1 : whi1), 32);
            i32x4 pw;
            pw[0] = (int)(hiL ? g0 : wlo0);
            pw[1] = (int)(hiL ? g1 : wlo1);
            pw[2] = (int)(hiL ? whi0 : g0);
            pw[3] = (int)(hiL ? whi1 : g1);
            const bf16x8 pa = __builtin_bit_cast(bf16x8, pw);
            o0 = __builtin_amdgcn_mfma_f32_32x32x16_bf16(pa, vf[ks],     o0, 0, 0, 0);
            o1 = __builtin_amdgcn_mfma_f32_32x32x16_bf16(pa, vf[4 + ks], o1, 0, 0, 0);
        }
        __builtin_amdgcn_s_setprio(0);
    }

    // epilogue: O[q=crow(r,hi)][d] / l[q]
    unsigned short* op = attn_b + ((size_t)b * TT + q0) * EE + h * HD;
#pragma unroll
    for (int r = 0; r < 16; ++r) {
        const int crow = (r & 3) + 8 * (r >> 2) + 4 * hiL;
        const float li = 1.f / __shfl(l_r, crow);
        op[(size_t)crow * EE + lq]      = f2bf(o0[r] * li);
        op[(size_t)crow * EE + 32 + lq] = f2bf(o1[r] * li);
    }
}

extern "C" void kernel_launch(void* const* d_in, const int* in_sizes, int n_in,
                              void* d_out, int out_size, void* d_ws, size_t ws_size,
                              hipStream_t stream) {
    const float* x     = (const float*)d_in[0];
    const float* wqkv  = (const float*)d_in[1];
    const float* wproj = (const float*)d_in[2];
    float* out = (float*)d_out;

    unsigned short* ws = (unsigned short*)d_ws;
    unsigned short* q_ws    = ws;                    // 32x32 frag order (pre-scaled)
    unsigned short* k_ws    = ws + (size_t)BTE;      // frag order
    unsigned short* v_ws    = ws + 2 * (size_t)BTE;  // frag order
    unsigned short* xb      = ws + 3 * (size_t)BTE;  // [8192][768]
    unsigned short* attn_b  = ws + 4 * (size_t)BTE;  // [8192][768]
    unsigned short* wqkv_t  = ws + 5 * (size_t)BTE;  // [2304][768]
    unsigned short* wproj_t = wqkv_t + (size_t)2304 * 768;

    convx_kernel<<<BTE / 2048, 256, 0, stream>>>(x, xb);
    transw_kernel<<<dim3(2304 / 64, KK / 64), 256, 0, stream>>>(wqkv, wqkv_t, 2304);
    transw_kernel<<<dim3(768 / 64, KK / 64), 256, 0, stream>>>(wproj, wproj_t, 768);

    mfma_gemm_kernel<0><<<dim3(2304 / 128, 8192 / 128), 256, 0, stream>>>(
        xb, wqkv_t, q_ws, k_ws, v_ws, nullptr);
    attn_kernel<<<dim3(BB * HH, TT / 32), 64, 0, stream>>>(q_ws, k_ws, v_ws, attn_b);
    mfma_gemm_kernel<1><<<dim3(EE / 128, 8192 / 128), 256, 0, stream>>>(
        attn_b, wproj_t, nullptr, nullptr, nullptr, out);
}